// Round 13
// baseline (962.877 us; speedup 1.0000x reference)
//
#include <hip/hip_runtime.h>
#include <stdint.h>

typedef unsigned int u32;
typedef unsigned long long u64;
typedef __attribute__((ext_vector_type(8))) short v8s;   // 8 bf16 = 4 VGPR (MFMA A/B frag)
typedef __attribute__((ext_vector_type(4))) float v4f;   // MFMA C/D frag

#define HH 64
#define WW 96
#define HW 6144
#define CC 512
#define NANCH 55296
#define PRE 6000
#define POST 300
#define CAP 8192
#define PW 98
#define PH 66
#define ICPAD 40

__device__ __constant__ float c_aw[9] = {184.f,368.f,736.f,128.f,256.f,512.f,88.f,176.f,352.f};
__device__ __constant__ float c_ah[9] = {96.f,192.f,384.f,128.f,256.f,512.f,176.f,352.f,704.f};

__device__ __forceinline__ unsigned short bf16_rne(float x){
  u32 u = __float_as_uint(x);
  return (unsigned short)((u + 0x7FFFu + ((u >> 16) & 1u)) >> 16);
}
__device__ __forceinline__ u32 sortkey(float s){
  u32 u = __float_as_uint(s);
  return u ^ ((u & 0x80000000u) ? 0xFFFFFFFFu : 0x80000000u);
}

// ---------- K0: merged convert (X: 528 blocks, W: 512 blocks) + ws zeroing ----------
__global__ __launch_bounds__(256) void k_cvt(const float* __restrict__ X, const float* __restrict__ Wt,
                                             unsigned short* __restrict__ Xih, unsigned short* __restrict__ Xil,
                                             unsigned short* __restrict__ Wh2, unsigned short* __restrict__ Wl2,
                                             u32* __restrict__ zero_region){
  __shared__ float Ls[64][97];
  __shared__ float Ws[4608];
  const int b = blockIdx.x, tid = threadIdx.x;
  { int gid = b*256 + tid;
    if (gid < 131072) zero_region[gid] = 0u;          // hist + hist2
    if (gid < 16) zero_region[131072 + gid] = 0u; }   // ctr
  if (b < 528){
    const int rp  = b % 66;
    const int ic0 = (b / 66) * 64;
    const bool zrow = (rp == 0 || rp == PH-1);
    if (!zrow){
      int r = rp - 1;
      for (int i = tid; i < 6144; i += 256){
        int ii = i / 96, c = i - ii*96;
        Ls[ii][c] = X[(ic0+ii)*HW + r*WW + c];
      }
    }
    __syncthreads();
    for (int i = tid; i < PW*64; i += 256){
      int cp = i >> 6, icl = i & 63;
      float x = 0.f;
      if (!zrow && cp >= 1 && cp <= 96) x = Ls[icl][cp-1];
      unsigned short h = bf16_rne(x);
      float hf = __uint_as_float(((u32)h) << 16);
      unsigned short l = bf16_rne(x - hf);
      long o = ((long)(rp*PW + cp) << 9) + ic0 + icl;
      Xih[o] = h; Xil[o] = l;
    }
  } else {
    const int oc = b - 528;
    for (int i = tid; i < 4608; i += 256) Ws[i] = Wt[oc*4608 + i];
    __syncthreads();
    for (int i = tid; i < 4608; i += 256){
      int tap = i / 512, ic = i - tap*512;
      float x = Ws[ic*9 + tap];
      unsigned short h = bf16_rne(x);
      float hf = __uint_as_float(((u32)h) << 16);
      unsigned short l = bf16_rne(x - hf);
      long o = ((long)(tap*512 + oc) << 9) + ic;
      Wh2[o] = h; Wl2[o] = l;
    }
  }
}

// ---------- K1: MFMA conv, LDS-staged — R11 VERBATIM (190 us known-good, bit-exact) ----------
__global__ __launch_bounds__(256, 1) void k_conv3(
    const unsigned short* __restrict__ Xih, const unsigned short* __restrict__ Xil,
    const unsigned short* __restrict__ Wh2, const unsigned short* __restrict__ Wl2,
    const float* __restrict__ Bc, float* __restrict__ Y)
{
  __shared__ __attribute__((aligned(16))) unsigned short Ah[6*98*ICPAD];
  __shared__ __attribute__((aligned(16))) unsigned short Al[6*98*ICPAD];
  __shared__ __attribute__((aligned(16))) unsigned short Bh[9*32*ICPAD];
  __shared__ __attribute__((aligned(16))) unsigned short Bl[9*32*ICPAD];
  const int tid  = threadIdx.x;
  const int w    = tid >> 6;
  const int lane = tid & 63;
  const int lm   = lane & 15;
  const int q    = lane >> 4;
  const int y0   = blockIdx.x * 4;
  const int oc0  = blockIdx.y * 32;

  v4f acc[6][2];
  #pragma unroll
  for (int t = 0; t < 6; ++t)
    #pragma unroll
    for (int n = 0; n < 2; ++n)
      acc[t][n] = (v4f){0.f,0.f,0.f,0.f};

  for (int icg = 0; icg < 16; ++icg){
    __syncthreads();
    for (int it = tid; it < 4704; it += 256){
      int i4 = it & 7, rc = it >> 3;
      int c = rc % 98, r = rc / 98;
      long src = ((long)((y0 + r)*PW + c) << 9) + icg*32 + i4*4;
      int dst = (r*98 + c)*ICPAD + i4*4;
      *reinterpret_cast<u64*>(Ah + dst) = *reinterpret_cast<const u64*>(Xih + src);
      *reinterpret_cast<u64*>(Al + dst) = *reinterpret_cast<const u64*>(Xil + src);
    }
    for (int it = tid; it < 2304; it += 256){
      int i4 = it & 7, to = it >> 3;
      int oc = to & 31, tap = to >> 5;
      long src = ((long)(tap*512 + oc0 + oc) << 9) + icg*32 + i4*4;
      int dst = (tap*32 + oc)*ICPAD + i4*4;
      *reinterpret_cast<u64*>(Bh + dst) = *reinterpret_cast<const u64*>(Wh2 + src);
      *reinterpret_cast<u64*>(Bl + dst) = *reinterpret_cast<const u64*>(Wl2 + src);
    }
    __syncthreads();
    #pragma unroll
    for (int tap = 0; tap < 9; ++tap){
      const int dy = tap / 3, dx = tap - dy*3;
      v8s ah[6], al[6], bh[2], bl[2];
      #pragma unroll
      for (int t = 0; t < 6; ++t){
        int a = ((w + dy)*98 + 16*t + lm + dx)*ICPAD + q*8;
        ah[t] = *reinterpret_cast<const v8s*>(Ah + a);
        al[t] = *reinterpret_cast<const v8s*>(Al + a);
      }
      #pragma unroll
      for (int n = 0; n < 2; ++n){
        int a = (tap*32 + n*16 + lm)*ICPAD + q*8;
        bh[n] = *reinterpret_cast<const v8s*>(Bh + a);
        bl[n] = *reinterpret_cast<const v8s*>(Bl + a);
      }
      #pragma unroll
      for (int t = 0; t < 6; ++t)
        #pragma unroll
        for (int n = 0; n < 2; ++n){
          acc[t][n] = __builtin_amdgcn_mfma_f32_16x16x32_bf16(al[t], bl[n], acc[t][n], 0, 0, 0);
          acc[t][n] = __builtin_amdgcn_mfma_f32_16x16x32_bf16(al[t], bh[n], acc[t][n], 0, 0, 0);
          acc[t][n] = __builtin_amdgcn_mfma_f32_16x16x32_bf16(ah[t], bl[n], acc[t][n], 0, 0, 0);
          acc[t][n] = __builtin_amdgcn_mfma_f32_16x16x32_bf16(ah[t], bh[n], acc[t][n], 0, 0, 0);
        }
    }
  }
  const int yrow = y0 + w;
  #pragma unroll
  for (int n = 0; n < 2; ++n){
    int oc = oc0 + n*16 + lm;
    float b = Bc[oc];
    #pragma unroll
    for (int t = 0; t < 6; ++t){
      float4 v;
      v.x = fmaxf(acc[t][n].x + b, 0.f);
      v.y = fmaxf(acc[t][n].y + b, 0.f);
      v.z = fmaxf(acc[t][n].z + b, 0.f);
      v.w = fmaxf(acc[t][n].w + b, 0.f);
      *reinterpret_cast<float4*>(Y + (long)oc*HW + yrow*WW + 16*t + q*4) = v;
    }
  }
}

// ---------------- K2: 1x1 heads + softmax + box decode (+ hist) — verbatim ----------------
__global__ __launch_bounds__(256) void k_head(
    const float* __restrict__ Y, const float* __restrict__ cw,
    const float* __restrict__ cb, const float* __restrict__ bw,
    const float* __restrict__ bb, const float* __restrict__ info,
    float* __restrict__ scores, float4* __restrict__ boxes, u32* __restrict__ hist)
{
  __shared__ float Ys[4096];
  __shared__ float Wsh[4096];
  const int tid = threadIdx.x;
  const int p0  = blockIdx.x * 64;
  const int po  = tid & 15;
  const int oj  = tid >> 4;
  float accM[4][4], accC[4][4];
  #pragma unroll
  for (int p = 0; p < 4; ++p)
    #pragma unroll
    for (int k = 0; k < 4; ++k){ accM[p][k] = 0.f; accC[p][k] = 0.f; }

  for (int c0 = 0; c0 < CC; c0 += 64){
    __syncthreads();
    for (int i = tid; i < 4096; i += 256){
      int c = i >> 6, p = i & 63;
      Ys[i] = Y[(c0 + c) * HW + p0 + p];
    }
    for (int i = tid; i < 4096; i += 256){
      int c = i >> 6, o = i & 63;
      int gc = c0 + c;
      float v = 0.f;
      if (o < 18) v = cw[o * 512 + gc];
      else if (o < 54) v = bw[(o - 18) * 512 + gc];
      Wsh[i] = v;
    }
    __syncthreads();
    for (int c = 0; c < 64; ++c){
      const float4 xv = *reinterpret_cast<const float4*>(Ys + c*64 + po*4);
      float xa[4] = {xv.x, xv.y, xv.z, xv.w};
      const float* wrd = Wsh + c*64 + oj;
      float wv[4] = {wrd[0], wrd[16], wrd[32], wrd[48]};
      #pragma unroll
      for (int p = 0; p < 4; ++p)
        #pragma unroll
        for (int k = 0; k < 4; ++k)
          accC[p][k] = __fmaf_rn(xa[p], wv[k], accC[p][k]);
    }
    #pragma unroll
    for (int p = 0; p < 4; ++p)
      #pragma unroll
      for (int k = 0; k < 4; ++k){ accM[p][k] += accC[p][k]; accC[p][k] = 0.f; }
  }
  __syncthreads();
  #pragma unroll
  for (int p = 0; p < 4; ++p)
    #pragma unroll
    for (int k = 0; k < 4; ++k){
      int o = oj + 16*k;
      float bias = (o < 18) ? cb[o] : ((o < 54) ? bb[o - 18] : 0.f);
      Ys[(po*4 + p)*64 + o] = accM[p][k] + bias;
    }
  __syncthreads();
  float imH = info[0], imW = info[1], imS = info[2];
  for (int it = tid; it < 576; it += 256){
    int pl = it / 9;
    int a  = it - pl*9;
    const float* L = Ys + pl*64;
    float l0 = L[a], l1 = L[9 + a];
    float mx = fmaxf(l0, l1);
    float e0 = expf(l0 - mx), e1 = expf(l1 - mx);
    float sc = e1 / (e0 + e1);
    float d0 = L[18 + a*4 + 0], d1 = L[18 + a*4 + 1];
    float d2 = L[18 + a*4 + 2], d3 = L[18 + a*4 + 3];
    int pos = p0 + pl;
    int yy = pos / 96;
    int xx = pos - yy * 96;
    float aw = c_aw[a], ah = c_ah[a];
    float acx = (float)(xx * 16 + 8);
    float acy = (float)(yy * 16 + 8);
    float cx = __fadd_rn(__fmul_rn(d0, aw), acx);
    float cy = __fadd_rn(__fmul_rn(d1, ah), acy);
    float pw = __fmul_rn(expf(d2), aw);
    float ph = __fmul_rn(expf(d3), ah);
    float hx = __fmul_rn(0.5f, pw);
    float hy = __fmul_rn(0.5f, ph);
    float x1 = fminf(fmaxf(__fadd_rn(cx, -hx), 0.f), imW - 1.f);
    float y1 = fminf(fmaxf(__fadd_rn(cy, -hy), 0.f), imH - 1.f);
    float x2 = fminf(fmaxf(__fadd_rn(cx,  hx), 0.f), imW - 1.f);
    float y2 = fminf(fmaxf(__fadd_rn(cy,  hy), 0.f), imH - 1.f);
    float ms = 16.f * imS;
    bool keep = ((x2 - x1 + 1.f) >= ms) && ((y2 - y1 + 1.f) >= ms);
    int g = pos * 9 + a;
    float val = keep ? sc : -__builtin_inff();
    scores[g] = val;
    boxes[g]  = make_float4(x1, y1, x2, y2);
    atomicAdd(&hist[sortkey(val) >> 16], 1u);
  }
}

// ---------- K3: fused selection — thresh1+hist2+thresh2+compact, ONE block (block barriers only) ----------
// Phase logic verbatim from R9's four kernels; the two serial 64-bin global walks
// are LDS-staged (R10-proven bs[] pattern). T16/above/K32 live in LDS only.
__global__ __launch_bounds__(1024) void k_sel(const u32* __restrict__ hist, u32* __restrict__ hist2,
                                              const float* __restrict__ scores,
                                              u32* __restrict__ ctr, u64* __restrict__ keys){
  __shared__ u32 cs[1024];
  __shared__ u32 bs[64];
  __shared__ int selg;
  __shared__ u32 afterv, T16s, aboves, K32s;
  const int t = threadIdx.x;
  const int b0 = t * 64;

  // ---- phase 1: thresh1 ----
  if (t == 0) selg = -1;
  __syncthreads();
  { u32 s = 0;
    for (int i = 0; i < 64; ++i) s += hist[b0 + i];
    cs[t] = s; }
  __syncthreads();
  for (int off = 1; off < 1024; off <<= 1){
    u32 v = cs[t];
    u32 ad = (t + off < 1024) ? cs[t + off] : 0u;
    __syncthreads();
    cs[t] = v + ad;
    __syncthreads();
  }
  { u32 here  = cs[t];
    u32 after = (t < 1023) ? cs[t + 1] : 0u;
    if (here >= 6000u && after < 6000u){ selg = t; afterv = after; } }
  __syncthreads();
  { int g = selg;
    if (g >= 0 && t < 64) bs[t] = hist[g*64 + t];
    __syncthreads();
    if (t == 0){
      if (g < 0){ T16s = 0u; aboves = 0u; }
      else {
        u32 acc = afterv;
        for (int b = 63; b >= 0; --b){
          u32 h = bs[b];
          acc += h;
          if (acc >= 6000u){ T16s = (u32)(g*64 + b); aboves = acc - h; break; }
        }
      }
    } }
  __syncthreads();

  // ---- phase 2: hist2 (global buffer, zeroed by k_cvt) ----
  { u32 pfx = T16s;
    for (int i = t; i < NANCH; i += 1024){
      u32 key = sortkey(scores[i]);
      if ((key >> 16) == pfx) atomicAdd(&hist2[key & 0xFFFFu], 1u);
    } }
  __threadfence();
  __syncthreads();

  // ---- phase 3: thresh2 ----
  if (t == 0) selg = -1;
  __syncthreads();
  const u32 target = 6000u - aboves;
  { u32 s = 0;
    for (int i = 0; i < 64; ++i) s += hist2[b0 + i];
    cs[t] = s; }
  __syncthreads();
  for (int off = 1; off < 1024; off <<= 1){
    u32 v = cs[t];
    u32 ad = (t + off < 1024) ? cs[t + off] : 0u;
    __syncthreads();
    cs[t] = v + ad;
    __syncthreads();
  }
  { u32 here  = cs[t];
    u32 after = (t < 1023) ? cs[t + 1] : 0u;
    if (here >= target && after < target){ selg = t; afterv = after; } }
  __syncthreads();
  { int g = selg;
    if (g >= 0 && t < 64) bs[t] = hist2[g*64 + t];
    __syncthreads();
    if (t == 0){
      if (g < 0) K32s = (T16s << 16);
      else {
        u32 acc = afterv;
        for (int b = 63; b >= 0; --b){
          u32 h = bs[b];
          acc += h;
          if (acc >= target){ K32s = (T16s << 16) | (u32)(g*64 + b); break; }
        }
      }
      ctr[4] = 6000u;          // finiteN init for k_rank's atomicMin
    } }
  __syncthreads();

  // ---- phase 4: compact ----
  { u32 K = K32s;
    for (int i = t; i < NANCH; i += 1024){
      u32 key = sortkey(scores[i]);
      if (key >= K){
        u32 pos = atomicAdd(&ctr[0], 1u);
        if (pos < CAP) keys[pos] = ((u64)key << 32) | (u64)(u32)(~(u32)i);
      }
    } }
}

// ---------------- K-rank (verbatim) ----------------
__global__ __launch_bounds__(128) void k_rank(const u64* __restrict__ keys, u32* __restrict__ ctr,
                                              const float4* __restrict__ boxes,
                                              float4* __restrict__ topB, float* __restrict__ topA){
  __shared__ u64 ks[2048];
  const int t  = threadIdx.x;
  const int gi = blockIdx.x * 128 + t;
  u32 count = ctr[0]; if (count > CAP) count = CAP;
  u64 my = (gi < (int)count) ? keys[gi] : 0ull;
  int rank = 0;
  for (int c0 = 0; c0 < CAP; c0 += 2048){
    __syncthreads();
    for (int s = t; s < 2048; s += 128){
      int j = c0 + s;
      ks[s] = (j < (int)count) ? keys[j] : 0ull;
    }
    __syncthreads();
    if (gi < (int)count){
      const ulonglong2* kp = reinterpret_cast<const ulonglong2*>(ks);
      #pragma unroll 8
      for (int s = 0; s < 1024; ++s){
        ulonglong2 kv = kp[s];
        rank += (kv.x > my) + (kv.y > my);
      }
    }
  }
  if (gi < (int)count && rank < PRE){
    if (!((my >> 32) & 0x80000000ull))
      atomicMin((int*)(ctr + 4), rank);
    u32 idx = ~(u32)my;
    float4 bv = make_float4(0.f,0.f,0.f,0.f);
    float area = 1.f;
    if (idx < NANCH){
      bv = boxes[idx];
      area = (bv.z - bv.x + 1.f) * (bv.w - bv.y + 1.f);
    }
    topB[rank] = bv;
    topA[rank] = area;
  }
}

// ---------- K5: fused NMS — boxes LDS/register-resident, IoU recomputed (no M matrix) ----------
// Replaces k_iou + k_reduce. Per-step: wave-ballot first-clear-bit on LDS supp,
// then 1024 threads each test their 6 register-held boxes vs the pick (IoU expr
// and area expr BIT-IDENTICAL to old k_iou/k_rank). Setting bits for j<i is
// harmless: pick = first unsuppressed, so all j<i are picked-or-suppressed.
__global__ __launch_bounds__(1024) void k_nms2(const float4* __restrict__ topB,
                                               const u32* __restrict__ ctr, float* __restrict__ out){
  __shared__ float4 bxs[PRE];      // 96 KB
  __shared__ u32 supp[188];
  __shared__ int kept[POST];
  __shared__ int wf[16];
  __shared__ int selS;
  const int t    = threadIdx.x;
  const int wv   = t >> 6;
  const int lane = t & 63;

  int validN = (int)ctr[0];
  int finN   = (int)ctr[4];
  if (finN < validN) validN = finN;
  if (validN > PRE)  validN = PRE;

  float4 rb[6]; float ra[6];
  #pragma unroll
  for (int m = 0; m < 6; ++m){
    int j = t + 1024*m;
    if (j < PRE){
      float4 b = topB[j];
      bxs[j] = b;
      rb[m] = b;
      ra[m] = (b.z - b.x + 1.f) * (b.w - b.y + 1.f);
    } else { rb[m] = make_float4(0.f,0.f,0.f,0.f); ra[m] = 1.f; }
  }
  if (t < 188){
    int lo = t * 32;
    u32 v;
    if (lo + 32 <= validN) v = 0u;
    else if (lo >= validN) v = 0xFFFFFFFFu;
    else v = ~((1u << (validN - lo)) - 1u);
    supp[t] = v;
  }
  __syncthreads();

  for (int k = 0; k < POST; ++k){
    bool has = (t < 188) && (supp[t] != 0xFFFFFFFFu);
    u64 bal = __ballot(has);
    if (lane == 0) wf[wv] = bal ? (wv*64 + (int)__ffsll((unsigned long long)bal) - 1) : 10000;
    __syncthreads();
    if (t == 0){
      int w0 = wf[0], w1 = wf[1], w2 = wf[2];
      int wmin = w0 < w1 ? w0 : w1;
      wmin = wmin < w2 ? wmin : w2;
      int i = -1;
      if (wmin < 10000) i = wmin*32 + (__ffs((int)(~supp[wmin])) - 1);
      selS = i;
      kept[k] = i;
    }
    __syncthreads();
    int i = selS;
    if (i >= 0){
      float4 bi = bxs[i];
      float ai = (bi.z - bi.x + 1.f) * (bi.w - bi.y + 1.f);
      #pragma unroll
      for (int m = 0; m < 6; ++m){
        int j = t + 1024*m;
        if (j < PRE){
          float xx1 = fmaxf(bi.x, rb[m].x);
          float yy1 = fmaxf(bi.y, rb[m].y);
          float xx2 = fminf(bi.z, rb[m].z);
          float yy2 = fminf(bi.w, rb[m].w);
          float iw = fmaxf(xx2 - xx1 + 1.f, 0.f);
          float ih = fmaxf(yy2 - yy1 + 1.f, 0.f);
          float inter = iw * ih;
          float iou = inter / (ai + ra[m] - inter);
          if (iou > 0.7f) atomicOr(&supp[j >> 5], 1u << (j & 31));  // self: iou=1 -> advances
        }
      }
    }
    __syncthreads();
  }
  for (int q = t; q < 1500; q += 1024){
    int r = q / 5, c = q - r*5;
    int i = kept[r];
    float v = 0.f;
    if (i >= 0 && c > 0){
      float4 b = bxs[i];
      v = (c == 1) ? b.x : (c == 2) ? b.y : (c == 3) ? b.z : b.w;
    }
    out[q] = v;
  }
}

// ---------------- launch ----------------
extern "C" void kernel_launch(void* const* d_in, const int* in_sizes, int n_in,
                              void* d_out, int out_size, void* d_ws, size_t ws_size,
                              hipStream_t stream)
{
  const float* fm   = (const float*)d_in[0];
  const float* info = (const float*)d_in[1];
  const float* cw3  = (const float*)d_in[2];
  const float* cb3  = (const float*)d_in[3];
  const float* clw  = (const float*)d_in[4];
  const float* clb  = (const float*)d_in[5];
  const float* bbw  = (const float*)d_in[6];
  const float* bbb  = (const float*)d_in[7];
  float* out = (float*)d_out;

  char* base = (char*)d_ws;
  u32*   hist   = (u32*)  (base + 0);          // 65536 u32
  u32*   hist2  = (u32*)  (base + 262144);     // 65536 u32
  u32*   ctr    = (u32*)  (base + 524288);     // [0]=count [4]=finiteN (others spare)
  float* Y      = (float*)(base + 524544);     // 12.58 MB
  float* scores = (float*)(base + 13107456);
  float4* boxes = (float4*)(base + 13328640);
  u64*   keys   = (u64*)  (base + 14213376);
  float4* topB  = (float4*)(base + 14278912);
  float* topA   = (float*)(base + 14375168);
  unsigned short* Xih = (unsigned short*)(base + 14399488);
  unsigned short* Xil = (unsigned short*)(base + 21022720);
  unsigned short* Wh2 = (unsigned short*)(base + 27645952);
  unsigned short* Wl2 = (unsigned short*)(base + 32364544);
  // total ws use: ~37.1 MB

  k_cvt  <<<1040, 256, 0, stream>>>(fm, cw3, Xih, Xil, Wh2, Wl2, (u32*)base);
  k_conv3<<<dim3(16, 16), 256, 0, stream>>>(Xih, Xil, Wh2, Wl2, cb3, Y);
  k_head <<<96,  256, 0, stream>>>(Y, clw, clb, bbw, bbb, info, scores, boxes, hist);
  k_sel  <<<1,  1024, 0, stream>>>(hist, hist2, scores, ctr, keys);
  k_rank <<<64,  128, 0, stream>>>(keys, ctr, boxes, topB, topA);
  k_nms2 <<<1,  1024, 0, stream>>>(topB, ctr, out);
}

// Round 14
// 849.125 us; speedup vs baseline: 1.1340x; 1.1340x over previous
//
#include <hip/hip_runtime.h>
#include <stdint.h>

typedef unsigned int u32;
typedef unsigned long long u64;
typedef __attribute__((ext_vector_type(8))) short v8s;   // 8 bf16 = 4 VGPR (MFMA A/B frag)
typedef __attribute__((ext_vector_type(4))) float v4f;   // MFMA C/D frag

#define HH 64
#define WW 96
#define HW 6144
#define CC 512
#define NANCH 55296
#define PRE 6000
#define POST 300
#define CAP 8192
#define PW 98
#define PH 66
#define ICPAD 40

__device__ __constant__ float c_aw[9] = {184.f,368.f,736.f,128.f,256.f,512.f,88.f,176.f,352.f};
__device__ __constant__ float c_ah[9] = {96.f,192.f,384.f,128.f,256.f,512.f,176.f,352.f,704.f};

__device__ __forceinline__ unsigned short bf16_rne(float x){
  u32 u = __float_as_uint(x);
  return (unsigned short)((u + 0x7FFFu + ((u >> 16) & 1u)) >> 16);
}
__device__ __forceinline__ u32 sortkey(float s){
  u32 u = __float_as_uint(s);
  return u ^ ((u & 0x80000000u) ? 0xFFFFFFFFu : 0x80000000u);
}

// ---------- K0: merged convert (X: 528 blocks, W: 512 blocks) + ws zeroing ----------
__global__ __launch_bounds__(256) void k_cvt(const float* __restrict__ X, const float* __restrict__ Wt,
                                             unsigned short* __restrict__ Xih, unsigned short* __restrict__ Xil,
                                             unsigned short* __restrict__ Wh2, unsigned short* __restrict__ Wl2,
                                             u32* __restrict__ zero_region){
  __shared__ float Ls[64][97];
  __shared__ float Ws[4608];
  const int b = blockIdx.x, tid = threadIdx.x;
  { int gid = b*256 + tid;
    if (gid < 131072) zero_region[gid] = 0u;          // hist + hist2
    if (gid < 16) zero_region[131072 + gid] = 0u; }   // ctr
  if (b < 528){
    const int rp  = b % 66;
    const int ic0 = (b / 66) * 64;
    const bool zrow = (rp == 0 || rp == PH-1);
    if (!zrow){
      int r = rp - 1;
      for (int i = tid; i < 6144; i += 256){
        int ii = i / 96, c = i - ii*96;
        Ls[ii][c] = X[(ic0+ii)*HW + r*WW + c];
      }
    }
    __syncthreads();
    for (int i = tid; i < PW*64; i += 256){
      int cp = i >> 6, icl = i & 63;
      float x = 0.f;
      if (!zrow && cp >= 1 && cp <= 96) x = Ls[icl][cp-1];
      unsigned short h = bf16_rne(x);
      float hf = __uint_as_float(((u32)h) << 16);
      unsigned short l = bf16_rne(x - hf);
      long o = ((long)(rp*PW + cp) << 9) + ic0 + icl;
      Xih[o] = h; Xil[o] = l;
    }
  } else {
    const int oc = b - 528;
    for (int i = tid; i < 4608; i += 256) Ws[i] = Wt[oc*4608 + i];
    __syncthreads();
    for (int i = tid; i < 4608; i += 256){
      int tap = i / 512, ic = i - tap*512;
      float x = Ws[ic*9 + tap];
      unsigned short h = bf16_rne(x);
      float hf = __uint_as_float(((u32)h) << 16);
      unsigned short l = bf16_rne(x - hf);
      long o = ((long)(tap*512 + oc) << 9) + ic;
      Wh2[o] = h; Wl2[o] = l;
    }
  }
}

// ---------- K1: MFMA conv, LDS-staged — R11 VERBATIM (190 us known-good, bit-exact) ----------
__global__ __launch_bounds__(256, 1) void k_conv3(
    const unsigned short* __restrict__ Xih, const unsigned short* __restrict__ Xil,
    const unsigned short* __restrict__ Wh2, const unsigned short* __restrict__ Wl2,
    const float* __restrict__ Bc, float* __restrict__ Y)
{
  __shared__ __attribute__((aligned(16))) unsigned short Ah[6*98*ICPAD];
  __shared__ __attribute__((aligned(16))) unsigned short Al[6*98*ICPAD];
  __shared__ __attribute__((aligned(16))) unsigned short Bh[9*32*ICPAD];
  __shared__ __attribute__((aligned(16))) unsigned short Bl[9*32*ICPAD];
  const int tid  = threadIdx.x;
  const int w    = tid >> 6;
  const int lane = tid & 63;
  const int lm   = lane & 15;
  const int q    = lane >> 4;
  const int y0   = blockIdx.x * 4;
  const int oc0  = blockIdx.y * 32;

  v4f acc[6][2];
  #pragma unroll
  for (int t = 0; t < 6; ++t)
    #pragma unroll
    for (int n = 0; n < 2; ++n)
      acc[t][n] = (v4f){0.f,0.f,0.f,0.f};

  for (int icg = 0; icg < 16; ++icg){
    __syncthreads();
    for (int it = tid; it < 4704; it += 256){
      int i4 = it & 7, rc = it >> 3;
      int c = rc % 98, r = rc / 98;
      long src = ((long)((y0 + r)*PW + c) << 9) + icg*32 + i4*4;
      int dst = (r*98 + c)*ICPAD + i4*4;
      *reinterpret_cast<u64*>(Ah + dst) = *reinterpret_cast<const u64*>(Xih + src);
      *reinterpret_cast<u64*>(Al + dst) = *reinterpret_cast<const u64*>(Xil + src);
    }
    for (int it = tid; it < 2304; it += 256){
      int i4 = it & 7, to = it >> 3;
      int oc = to & 31, tap = to >> 5;
      long src = ((long)(tap*512 + oc0 + oc) << 9) + icg*32 + i4*4;
      int dst = (tap*32 + oc)*ICPAD + i4*4;
      *reinterpret_cast<u64*>(Bh + dst) = *reinterpret_cast<const u64*>(Wh2 + src);
      *reinterpret_cast<u64*>(Bl + dst) = *reinterpret_cast<const u64*>(Wl2 + src);
    }
    __syncthreads();
    #pragma unroll
    for (int tap = 0; tap < 9; ++tap){
      const int dy = tap / 3, dx = tap - dy*3;
      v8s ah[6], al[6], bh[2], bl[2];
      #pragma unroll
      for (int t = 0; t < 6; ++t){
        int a = ((w + dy)*98 + 16*t + lm + dx)*ICPAD + q*8;
        ah[t] = *reinterpret_cast<const v8s*>(Ah + a);
        al[t] = *reinterpret_cast<const v8s*>(Al + a);
      }
      #pragma unroll
      for (int n = 0; n < 2; ++n){
        int a = (tap*32 + n*16 + lm)*ICPAD + q*8;
        bh[n] = *reinterpret_cast<const v8s*>(Bh + a);
        bl[n] = *reinterpret_cast<const v8s*>(Bl + a);
      }
      #pragma unroll
      for (int t = 0; t < 6; ++t)
        #pragma unroll
        for (int n = 0; n < 2; ++n){
          acc[t][n] = __builtin_amdgcn_mfma_f32_16x16x32_bf16(al[t], bl[n], acc[t][n], 0, 0, 0);
          acc[t][n] = __builtin_amdgcn_mfma_f32_16x16x32_bf16(al[t], bh[n], acc[t][n], 0, 0, 0);
          acc[t][n] = __builtin_amdgcn_mfma_f32_16x16x32_bf16(ah[t], bl[n], acc[t][n], 0, 0, 0);
          acc[t][n] = __builtin_amdgcn_mfma_f32_16x16x32_bf16(ah[t], bh[n], acc[t][n], 0, 0, 0);
        }
    }
  }
  const int yrow = y0 + w;
  #pragma unroll
  for (int n = 0; n < 2; ++n){
    int oc = oc0 + n*16 + lm;
    float b = Bc[oc];
    #pragma unroll
    for (int t = 0; t < 6; ++t){
      float4 v;
      v.x = fmaxf(acc[t][n].x + b, 0.f);
      v.y = fmaxf(acc[t][n].y + b, 0.f);
      v.z = fmaxf(acc[t][n].z + b, 0.f);
      v.w = fmaxf(acc[t][n].w + b, 0.f);
      *reinterpret_cast<float4*>(Y + (long)oc*HW + yrow*WW + 16*t + q*4) = v;
    }
  }
}

// ---------------- K2: 1x1 heads + softmax + box decode (+ hist) — verbatim ----------------
__global__ __launch_bounds__(256) void k_head(
    const float* __restrict__ Y, const float* __restrict__ cw,
    const float* __restrict__ cb, const float* __restrict__ bw,
    const float* __restrict__ bb, const float* __restrict__ info,
    float* __restrict__ scores, float4* __restrict__ boxes, u32* __restrict__ hist)
{
  __shared__ float Ys[4096];
  __shared__ float Wsh[4096];
  const int tid = threadIdx.x;
  const int p0  = blockIdx.x * 64;
  const int po  = tid & 15;
  const int oj  = tid >> 4;
  float accM[4][4], accC[4][4];
  #pragma unroll
  for (int p = 0; p < 4; ++p)
    #pragma unroll
    for (int k = 0; k < 4; ++k){ accM[p][k] = 0.f; accC[p][k] = 0.f; }

  for (int c0 = 0; c0 < CC; c0 += 64){
    __syncthreads();
    for (int i = tid; i < 4096; i += 256){
      int c = i >> 6, p = i & 63;
      Ys[i] = Y[(c0 + c) * HW + p0 + p];
    }
    for (int i = tid; i < 4096; i += 256){
      int c = i >> 6, o = i & 63;
      int gc = c0 + c;
      float v = 0.f;
      if (o < 18) v = cw[o * 512 + gc];
      else if (o < 54) v = bw[(o - 18) * 512 + gc];
      Wsh[i] = v;
    }
    __syncthreads();
    for (int c = 0; c < 64; ++c){
      const float4 xv = *reinterpret_cast<const float4*>(Ys + c*64 + po*4);
      float xa[4] = {xv.x, xv.y, xv.z, xv.w};
      const float* wrd = Wsh + c*64 + oj;
      float wv[4] = {wrd[0], wrd[16], wrd[32], wrd[48]};
      #pragma unroll
      for (int p = 0; p < 4; ++p)
        #pragma unroll
        for (int k = 0; k < 4; ++k)
          accC[p][k] = __fmaf_rn(xa[p], wv[k], accC[p][k]);
    }
    #pragma unroll
    for (int p = 0; p < 4; ++p)
      #pragma unroll
      for (int k = 0; k < 4; ++k){ accM[p][k] += accC[p][k]; accC[p][k] = 0.f; }
  }
  __syncthreads();
  #pragma unroll
  for (int p = 0; p < 4; ++p)
    #pragma unroll
    for (int k = 0; k < 4; ++k){
      int o = oj + 16*k;
      float bias = (o < 18) ? cb[o] : ((o < 54) ? bb[o - 18] : 0.f);
      Ys[(po*4 + p)*64 + o] = accM[p][k] + bias;
    }
  __syncthreads();
  float imH = info[0], imW = info[1], imS = info[2];
  for (int it = tid; it < 576; it += 256){
    int pl = it / 9;
    int a  = it - pl*9;
    const float* L = Ys + pl*64;
    float l0 = L[a], l1 = L[9 + a];
    float mx = fmaxf(l0, l1);
    float e0 = expf(l0 - mx), e1 = expf(l1 - mx);
    float sc = e1 / (e0 + e1);
    float d0 = L[18 + a*4 + 0], d1 = L[18 + a*4 + 1];
    float d2 = L[18 + a*4 + 2], d3 = L[18 + a*4 + 3];
    int pos = p0 + pl;
    int yy = pos / 96;
    int xx = pos - yy * 96;
    float aw = c_aw[a], ah = c_ah[a];
    float acx = (float)(xx * 16 + 8);
    float acy = (float)(yy * 16 + 8);
    float cx = __fadd_rn(__fmul_rn(d0, aw), acx);
    float cy = __fadd_rn(__fmul_rn(d1, ah), acy);
    float pw = __fmul_rn(expf(d2), aw);
    float ph = __fmul_rn(expf(d3), ah);
    float hx = __fmul_rn(0.5f, pw);
    float hy = __fmul_rn(0.5f, ph);
    float x1 = fminf(fmaxf(__fadd_rn(cx, -hx), 0.f), imW - 1.f);
    float y1 = fminf(fmaxf(__fadd_rn(cy, -hy), 0.f), imH - 1.f);
    float x2 = fminf(fmaxf(__fadd_rn(cx,  hx), 0.f), imW - 1.f);
    float y2 = fminf(fmaxf(__fadd_rn(cy,  hy), 0.f), imH - 1.f);
    float ms = 16.f * imS;
    bool keep = ((x2 - x1 + 1.f) >= ms) && ((y2 - y1 + 1.f) >= ms);
    int g = pos * 9 + a;
    float val = keep ? sc : -__builtin_inff();
    scores[g] = val;
    boxes[g]  = make_float4(x1, y1, x2, y2);
    atomicAdd(&hist[sortkey(val) >> 16], 1u);
  }
}

// ---------- K3: fused selection — thresh1+hist2+thresh2+compact, ONE block (R13-proven) ----------
__global__ __launch_bounds__(1024) void k_sel(const u32* __restrict__ hist, u32* __restrict__ hist2,
                                              const float* __restrict__ scores,
                                              u32* __restrict__ ctr, u64* __restrict__ keys){
  __shared__ u32 cs[1024];
  __shared__ u32 bs[64];
  __shared__ int selg;
  __shared__ u32 afterv, T16s, aboves, K32s;
  const int t = threadIdx.x;
  const int b0 = t * 64;

  if (t == 0) selg = -1;
  __syncthreads();
  { u32 s = 0;
    for (int i = 0; i < 64; ++i) s += hist[b0 + i];
    cs[t] = s; }
  __syncthreads();
  for (int off = 1; off < 1024; off <<= 1){
    u32 v = cs[t];
    u32 ad = (t + off < 1024) ? cs[t + off] : 0u;
    __syncthreads();
    cs[t] = v + ad;
    __syncthreads();
  }
  { u32 here  = cs[t];
    u32 after = (t < 1023) ? cs[t + 1] : 0u;
    if (here >= 6000u && after < 6000u){ selg = t; afterv = after; } }
  __syncthreads();
  { int g = selg;
    if (g >= 0 && t < 64) bs[t] = hist[g*64 + t];
    __syncthreads();
    if (t == 0){
      if (g < 0){ T16s = 0u; aboves = 0u; }
      else {
        u32 acc = afterv;
        for (int b = 63; b >= 0; --b){
          u32 h = bs[b];
          acc += h;
          if (acc >= 6000u){ T16s = (u32)(g*64 + b); aboves = acc - h; break; }
        }
      }
    } }
  __syncthreads();

  { u32 pfx = T16s;
    for (int i = t; i < NANCH; i += 1024){
      u32 key = sortkey(scores[i]);
      if ((key >> 16) == pfx) atomicAdd(&hist2[key & 0xFFFFu], 1u);
    } }
  __threadfence();
  __syncthreads();

  if (t == 0) selg = -1;
  __syncthreads();
  const u32 target = 6000u - aboves;
  { u32 s = 0;
    for (int i = 0; i < 64; ++i) s += hist2[b0 + i];
    cs[t] = s; }
  __syncthreads();
  for (int off = 1; off < 1024; off <<= 1){
    u32 v = cs[t];
    u32 ad = (t + off < 1024) ? cs[t + off] : 0u;
    __syncthreads();
    cs[t] = v + ad;
    __syncthreads();
  }
  { u32 here  = cs[t];
    u32 after = (t < 1023) ? cs[t + 1] : 0u;
    if (here >= target && after < target){ selg = t; afterv = after; } }
  __syncthreads();
  { int g = selg;
    if (g >= 0 && t < 64) bs[t] = hist2[g*64 + t];
    __syncthreads();
    if (t == 0){
      if (g < 0) K32s = (T16s << 16);
      else {
        u32 acc = afterv;
        for (int b = 63; b >= 0; --b){
          u32 h = bs[b];
          acc += h;
          if (acc >= target){ K32s = (T16s << 16) | (u32)(g*64 + b); break; }
        }
      }
      ctr[4] = 6000u;
    } }
  __syncthreads();

  { u32 K = K32s;
    for (int i = t; i < NANCH; i += 1024){
      u32 key = sortkey(scores[i]);
      if (key >= K){
        u32 pos = atomicAdd(&ctr[0], 1u);
        if (pos < CAP) keys[pos] = ((u64)key << 32) | (u64)(u32)(~(u32)i);
      }
    } }
}

// ---------------- K-rank (verbatim) ----------------
__global__ __launch_bounds__(128) void k_rank(const u64* __restrict__ keys, u32* __restrict__ ctr,
                                              const float4* __restrict__ boxes,
                                              float4* __restrict__ topB, float* __restrict__ topA){
  __shared__ u64 ks[2048];
  const int t  = threadIdx.x;
  const int gi = blockIdx.x * 128 + t;
  u32 count = ctr[0]; if (count > CAP) count = CAP;
  u64 my = (gi < (int)count) ? keys[gi] : 0ull;
  int rank = 0;
  for (int c0 = 0; c0 < CAP; c0 += 2048){
    __syncthreads();
    for (int s = t; s < 2048; s += 128){
      int j = c0 + s;
      ks[s] = (j < (int)count) ? keys[j] : 0ull;
    }
    __syncthreads();
    if (gi < (int)count){
      const ulonglong2* kp = reinterpret_cast<const ulonglong2*>(ks);
      #pragma unroll 8
      for (int s = 0; s < 1024; ++s){
        ulonglong2 kv = kp[s];
        rank += (kv.x > my) + (kv.y > my);
      }
    }
  }
  if (gi < (int)count && rank < PRE){
    if (!((my >> 32) & 0x80000000ull))
      atomicMin((int*)(ctr + 4), rank);
    u32 idx = ~(u32)my;
    float4 bv = make_float4(0.f,0.f,0.f,0.f);
    float area = 1.f;
    if (idx < NANCH){
      bv = boxes[idx];
      area = (bv.z - bv.x + 1.f) * (bv.w - bv.y + 1.f);
    }
    topB[rank] = bv;
    topA[rank] = area;
  }
}

// ---------------- NMS stage A: suppression bit-matrix M[6000][188] (R11 verbatim) ----------------
__global__ __launch_bounds__(256) void k_iou(const float4* __restrict__ topB, const float* __restrict__ topA,
                                             u32* __restrict__ M){
  __shared__ float4 jb[3072];
  const int tid = threadIdx.x;
  const int rr  = tid & 31;
  const int wg  = tid >> 5;
  const int i   = blockIdx.x * 32 + rr;
  float4 bi = make_float4(0.f,0.f,0.f,0.f); float ai = 1.f;
  if (i < PRE){ bi = topB[i]; ai = topA[i]; }
  for (int ph = 0; ph < 2; ++ph){
    __syncthreads();
    for (int s = tid; s < 3072; s += 256){
      int j = ph*3072 + s;
      jb[s] = (j < PRE) ? topB[j] : make_float4(0.f,0.f,0.f,0.f);
    }
    __syncthreads();
    if (i >= PRE) continue;
    int nw = (ph == 0) ? 96 : 92;
    #pragma unroll
    for (int m = 0; m < 12; ++m){
      int wl = wg + 8*m;
      if (wl >= nw) continue;
      int w = ph*96 + wl;
      int jbase = w * 32;
      if (jbase + 31 <= i){ M[(size_t)i*188 + w] = 0u; continue; }
      u32 bits = 0u;
      for (int s = 0; s < 32; ++s){
        int j = jbase + s;
        if (j <= i || j >= PRE) continue;
        float4 bj = jb[j - ph*3072];
        float aj = (bj.z - bj.x + 1.f) * (bj.w - bj.y + 1.f);
        float xx1 = fmaxf(bi.x, bj.x);
        float yy1 = fmaxf(bi.y, bj.y);
        float xx2 = fminf(bi.z, bj.z);
        float yy2 = fminf(bi.w, bj.w);
        float iw = fmaxf(xx2 - xx1 + 1.f, 0.f);
        float ih = fmaxf(yy2 - yy1 + 1.f, 0.f);
        float inter = iw * ih;
        float iou = inter / (ai + aj - inter);
        if (iou > 0.7f) bits |= (1u << s);
      }
      M[(size_t)i*188 + w] = bits;
    }
  }
}

// ---------------- NMS stage B: single-wave greedy scan (R11 verbatim — zero barriers) ----------------
__global__ __launch_bounds__(64) void k_reduce(const u32* __restrict__ M, const float4* __restrict__ topB,
                                               const u32* __restrict__ ctr, float* __restrict__ out){
  __shared__ int kept[POST];
  const int t = threadIdx.x;
  int validN = (int)ctr[0];
  int finN   = (int)ctr[4];
  if (finN < validN) validN = finN;
  if (validN > PRE)  validN = PRE;
  auto initw = [&](int w)->u32{
    if (w >= 188) return 0xFFFFFFFFu;
    int lo = w * 32;
    if (lo + 32 <= validN) return 0u;
    if (lo >= validN) return 0xFFFFFFFFu;
    return ~((1u << (validN - lo)) - 1u);
  };
  u32 s0 = initw(t), s1 = initw(64 + t), s2 = initw(128 + t);
  for (int k = 0; k < POST; ++k){
    int i = -1;
    u64 b0 = __ballot(s0 != 0xFFFFFFFFu);
    if (b0){
      int L = (int)__ffsll((unsigned long long)b0) - 1;
      u32 v = (u32)__shfl((int)s0, L, 64);
      i = L*32 + (__ffs((int)(~v)) - 1);
    } else {
      u64 b1 = __ballot(s1 != 0xFFFFFFFFu);
      if (b1){
        int L = (int)__ffsll((unsigned long long)b1) - 1;
        u32 v = (u32)__shfl((int)s1, L, 64);
        i = 2048 + L*32 + (__ffs((int)(~v)) - 1);
      } else {
        u64 b2 = __ballot(s2 != 0xFFFFFFFFu);
        if (b2){
          int L = (int)__ffsll((unsigned long long)b2) - 1;
          u32 v = (u32)__shfl((int)s2, L, 64);
          i = 4096 + L*32 + (__ffs((int)(~v)) - 1);
        }
      }
    }
    if (t == 0) kept[k] = i;
    if (i >= 0){
      const u32* row = M + (size_t)i * 188;
      u32 r0 = row[t];
      u32 r1 = (64 + t < 188) ? row[64 + t] : 0u;
      u32 r2 = (128 + t < 188) ? row[128 + t] : 0u;
      s0 |= r0; s1 |= r1; s2 |= r2;
      int iw = i >> 5, ib = i & 31;
      if (iw == t) s0 |= (1u << ib);
      else if (iw == 64 + t) s1 |= (1u << ib);
      else if (iw == 128 + t) s2 |= (1u << ib);
    }
  }
  __syncthreads();
  for (int q = t; q < 1500; q += 64){
    int r = q / 5, c = q - r*5;
    int i = kept[r];
    float v = 0.f;
    if (i >= 0 && c > 0){
      float4 bx = topB[i];
      v = (c == 1) ? bx.x : (c == 2) ? bx.y : (c == 3) ? bx.z : bx.w;
    }
    out[q] = v;
  }
}

// ---------------- launch ----------------
extern "C" void kernel_launch(void* const* d_in, const int* in_sizes, int n_in,
                              void* d_out, int out_size, void* d_ws, size_t ws_size,
                              hipStream_t stream)
{
  const float* fm   = (const float*)d_in[0];
  const float* info = (const float*)d_in[1];
  const float* cw3  = (const float*)d_in[2];
  const float* cb3  = (const float*)d_in[3];
  const float* clw  = (const float*)d_in[4];
  const float* clb  = (const float*)d_in[5];
  const float* bbw  = (const float*)d_in[6];
  const float* bbb  = (const float*)d_in[7];
  float* out = (float*)d_out;

  char* base = (char*)d_ws;
  u32*   hist   = (u32*)  (base + 0);          // 65536 u32
  u32*   hist2  = (u32*)  (base + 262144);     // 65536 u32
  u32*   ctr    = (u32*)  (base + 524288);     // [0]=count [4]=finiteN
  float* Y      = (float*)(base + 524544);     // 12.58 MB
  u32*   M      = (u32*)  (base + 524544);     // overlays Y (dead after k_head): 4.5 MB
  float* scores = (float*)(base + 13107456);
  float4* boxes = (float4*)(base + 13328640);
  u64*   keys   = (u64*)  (base + 14213376);
  float4* topB  = (float4*)(base + 14278912);
  float* topA   = (float*)(base + 14375168);
  unsigned short* Xih = (unsigned short*)(base + 14399488);
  unsigned short* Xil = (unsigned short*)(base + 21022720);
  unsigned short* Wh2 = (unsigned short*)(base + 27645952);
  unsigned short* Wl2 = (unsigned short*)(base + 32364544);
  // total ws use: ~37.1 MB

  k_cvt   <<<1040, 256, 0, stream>>>(fm, cw3, Xih, Xil, Wh2, Wl2, (u32*)base);
  k_conv3 <<<dim3(16, 16), 256, 0, stream>>>(Xih, Xil, Wh2, Wl2, cb3, Y);
  k_head  <<<96,  256, 0, stream>>>(Y, clw, clb, bbw, bbb, info, scores, boxes, hist);
  k_sel   <<<1,  1024, 0, stream>>>(hist, hist2, scores, ctr, keys);
  k_rank  <<<64,  128, 0, stream>>>(keys, ctr, boxes, topB, topA);
  k_iou   <<<188, 256, 0, stream>>>(topB, topA, M);
  k_reduce<<<1,    64, 0, stream>>>(M, topB, ctr, out);
}